// Round 8
// baseline (260.172 us; speedup 1.0000x reference)
//
#include <hip/hip_runtime.h>
#include <stdint.h>

#define EMBED 1024
#define NH 16
#define HD 64
#define SEQ 2048
#define BATCH 4
#define M_TOT (BATCH*SEQ)   // 8192
#define QSCALE 0.18033688011112042f   // log2(e)/sqrt(HD)

typedef __attribute__((ext_vector_type(8))) short short8;
typedef __attribute__((ext_vector_type(4))) float floatx4;
typedef __attribute__((ext_vector_type(4))) unsigned int uintx4;

__device__ __forceinline__ unsigned short f2bf(float f) {
    union { float f; unsigned int u; } v; v.f = f;
    unsigned int r = v.u + 0x7fffu + ((v.u >> 16) & 1u);
    return (unsigned short)(r >> 16);
}

__device__ __forceinline__ void load_lds16(const unsigned short* g, unsigned short* l) {
    __builtin_amdgcn_global_load_lds(
        (const __attribute__((address_space(1))) unsigned int*)g,
        (__attribute__((address_space(3))) unsigned int*)l, 16, 0, 0);
}

// ---- kernel 1: x fp32 -> bf16 ----
__global__ void cvt_x(const float* __restrict__ x, unsigned short* __restrict__ xb) {
    int i = (blockIdx.x * 256 + threadIdx.x) * 4;
    float4 v = *(const float4*)(x + i);
    ushort4 o;
    o.x = f2bf(v.x); o.y = f2bf(v.y); o.z = f2bf(v.z); o.w = f2bf(v.w);
    *(ushort4*)(xb + i) = o;
}

// ---- kernel 2: transpose W [k][n] fp32 -> WT [n][k] bf16 ----
__global__ void wtrans(const float* __restrict__ w0, const float* __restrict__ w1,
                       const float* __restrict__ w2, const float* __restrict__ w3,
                       unsigned short* __restrict__ t0, unsigned short* __restrict__ t1,
                       unsigned short* __restrict__ t2, unsigned short* __restrict__ t3) {
    __shared__ float tile[32][33];
    const float* W; unsigned short* T;
    switch (blockIdx.z) { case 0: W=w0; T=t0; break; case 1: W=w1; T=t1; break;
                          case 2: W=w2; T=t2; break; default: W=w3; T=t3; }
    int n0 = blockIdx.x * 32, k0 = blockIdx.y * 32;
    int tx = threadIdx.x, ty = threadIdx.y;
    #pragma unroll
    for (int i = 0; i < 4; i++)
        tile[ty + i*8][tx] = W[(k0 + ty + i*8) * EMBED + n0 + tx];
    __syncthreads();
    #pragma unroll
    for (int i = 0; i < 4; i++)
        T[(n0 + ty + i*8) * EMBED + k0 + tx] = f2bf(tile[tx][ty + i*8]);
}

// ---- kernel 3: 128x128 GEMM, BK=32, 4-buffer deep pipeline, conflict-free swizzle.
// (unchanged from round 7: out of top-5, < 70us for QKV)
#define GBUFS 8192   // ushorts per K-tile buffer (16KB: A 128x32 | B 128x32)

template<bool STG, int WAITN>
__device__ __forceinline__ void ktile(int t,
        const unsigned short* Abase, const unsigned short* Bbase,
        const unsigned short* Asrc, const unsigned short* Bsrc,
        unsigned short* sda, unsigned short* sdb, floatx4 (&acc)[4][2]) {
    const int bo = (t & 3) * GBUFS;
    short8 fA[4], fB[2];
    #pragma unroll
    for (int m=0;m<4;m++) fA[m] = *(const short8*)(Abase + bo + m*512);
    #pragma unroll
    for (int n=0;n<2;n++) fB[n] = *(const short8*)(Bbase + bo + n*512);
    if (STG) {
        const int buf_ = (t+3) & 3; const int ko_ = (t+3)*32;
        load_lds16(Asrc + ko_, sda + buf_*GBUFS);
        load_lds16(Bsrc + ko_, sdb + buf_*GBUFS);
    }
    #pragma unroll
    for (int m=0;m<4;m++)
      #pragma unroll
      for (int n=0;n<2;n++)
        acc[m][n] = __builtin_amdgcn_mfma_f32_16x16x32_bf16(fA[m], fB[n], acc[m][n], 0,0,0);
    if (WAITN == 4)      { asm volatile("s_waitcnt vmcnt(4)" ::: "memory"); asm volatile("s_barrier" ::: "memory"); }
    else if (WAITN == 2) { asm volatile("s_waitcnt vmcnt(2)" ::: "memory"); asm volatile("s_barrier" ::: "memory"); }
    else if (WAITN == 0) { asm volatile("s_waitcnt vmcnt(0)" ::: "memory"); asm volatile("s_barrier" ::: "memory"); }
}

template<int MODE>
__global__ __launch_bounds__(512, 4) void gemmk(
        const unsigned short* __restrict__ A, const unsigned short* __restrict__ BT,
        const float* __restrict__ b0, const float* __restrict__ b1, const float* __restrict__ b2,
        void* __restrict__ o0, void* __restrict__ o1, void* __restrict__ o2) {
    constexpr int BM = 128, BN = 128;
    __shared__ unsigned short lds[4*GBUFS];    // 64KB: 4 bufs
    const int tid = threadIdx.x;
    const int lane = tid & 63, wave = tid >> 6;
    const int quad = lane >> 4, l16 = lane & 15;
    const int wm = wave >> 2, wn = wave & 3;   // wave tile 64x32 at (wm*64, wn*32)
    const int id = blockIdx.x;
    constexpr int MS = (M_TOT/BM)/8;           // 8 m-blocks per XCD stripe
    const int xcd = id & 7, j = id >> 3;
    const int mblk = (xcd * MS + (j % MS)) * BM;
    const int nblk = (j / MS) * BN;

    // staging: thread tid = (row tid>>2, slot tid&3); slot s holds logical chunk
    // s ^ f(row), f(r) = (r&3)^((r>>2)&3)  (inverse-swizzled global source).
    const int srow = tid >> 2;
    const int scol = ((tid & 3) ^ (srow & 3) ^ ((srow >> 2) & 3)) * 8;
    const unsigned short* Asrc = A  + (size_t)(mblk + srow) * EMBED + scol;
    const unsigned short* Bsrc = BT + (size_t)(nblk + srow) * EMBED + scol;
    unsigned short* sda = lds + wave * 512;            // wave stages rows w*16..+15
    unsigned short* sdb = lds + BM*32 + wave * 512;

    // swizzled fragment read: row ..+l16, logical chunk quad at slot quad ^ f(l16)
    const int cs = (quad ^ (l16 & 3) ^ ((l16 >> 2) & 3)) * 8;
    const unsigned short* Abase = lds + (wm*64 + l16)*32 + cs;
    const unsigned short* Bbase = lds + BM*32 + (wn*32 + l16)*32 + cs;

    floatx4 acc[4][2];
    #pragma unroll
    for (int m=0;m<4;m++)
      #pragma unroll
      for (int n=0;n<2;n++) acc[m][n] = (floatx4){0.f,0.f,0.f,0.f};

    // prologue: stage tiles 0,1,2 (in order); vmcnt(4) completes tile 0 only
    #pragma unroll
    for (int p=0;p<3;p++) {
        load_lds16(Asrc + p*32, sda + p*GBUFS);
        load_lds16(Bsrc + p*32, sdb + p*GBUFS);
    }
    asm volatile("s_waitcnt vmcnt(4)" ::: "memory");
    asm volatile("s_barrier" ::: "memory");

    #pragma unroll 4
    for (int t = 0; t < 28; ++t)
        ktile<true,4>(t, Abase, Bbase, Asrc, Bsrc, sda, sdb, acc);
    ktile<true, 4>(28, Abase, Bbase, Asrc, Bsrc, sda, sdb, acc);  // stages ST(31)
    ktile<false,2>(29, Abase, Bbase, Asrc, Bsrc, sda, sdb, acc);
    ktile<false,0>(30, Abase, Bbase, Asrc, Bsrc, sda, sdb, acc);
    ktile<false,-1>(31, Abase, Bbase, Asrc, Bsrc, sda, sdb, acc);

    // epilogue: C/D layout col=lane&15, row=quad*4+reg
    if constexpr (MODE == 1) {
        float* O = (float*)o0;
        #pragma unroll
        for (int mt=0;mt<4;mt++)
          #pragma unroll
          for (int nt=0;nt<2;nt++) {
            int col = nblk + wn*32 + nt*16 + l16;
            float bv = b0[col];
            #pragma unroll
            for (int r=0;r<4;r++) {
                int row = mblk + wm*64 + mt*16 + quad*4 + r;
                O[(size_t)row * EMBED + col] = acc[mt][nt][r] + bv;
            }
          }
    } else {
        int which = nblk >> 10;
        const float* bs = (which==0) ? b0 : (which==1) ? b1 : b2;
        if (which < 2) {
            unsigned short* O = (unsigned short*)((which==0) ? o0 : o1);
            float sc = (which==0) ? QSCALE : 1.f;
            #pragma unroll
            for (int mt=0;mt<4;mt++)
              #pragma unroll
              for (int nt=0;nt<2;nt++) {
                int coll = (nblk & 1023) + wn*32 + nt*16 + l16;
                float bv = bs[coll];
                int h = coll >> 6, d = coll & 63;
                #pragma unroll
                for (int r=0;r<4;r++) {
                    int row = mblk + wm*64 + mt*16 + quad*4 + r;
                    int b = row >> 11, s = row & 2047;
                    O[((size_t)(b*NH + h)*SEQ + s)*HD + d] = f2bf((acc[mt][nt][r] + bv) * sc);
                }
              }
        } else {
            // V: padded LDS transpose (stride 136 ushorts); tau-perm on write side.
            unsigned short* T = lds;
            unsigned short* OV = (unsigned short*)o2;
            size_t rowbase = ((size_t)((mblk >> 11)*1024 + (nblk & 1023))) * SEQ + (mblk & 2047);
            __syncthreads();     // all K-loop LDS reads complete before overwrite
            #pragma unroll
            for (int nt=0;nt<2;nt++) {
                int cloc = wn*32 + nt*16 + l16;            // local col 0..127
                float bv = bs[(nblk & 1023) + cloc];
                #pragma unroll
                for (int mt=0;mt<4;mt++) {
                    int row0 = wm*64 + mt*16 + quad*4;     // local row, mult of 4
                    int sp0 = (row0 & ~31) | (((row0 >> 2) & 3) << 3) | (((row0 >> 4) & 1) << 2);
                    ushort4 w;
                    w.x = f2bf(acc[mt][nt][0] + bv);
                    w.y = f2bf(acc[mt][nt][1] + bv);
                    w.z = f2bf(acc[mt][nt][2] + bv);
                    w.w = f2bf(acc[mt][nt][3] + bv);
                    *(ushort4*)(T + cloc*136 + sp0) = w;
                }
            }
            __syncthreads();
            int s0 = (lane & 15) * 8, dloc = lane >> 4;    // 16 s-chunks x 4 cols
            #pragma unroll
            for (int i=0;i<4;i++) {
                int c = wave*16 + i*4 + dloc;              // local col 0..127
                short8 v = *(const short8*)(T + c*136 + s0);
                *(short8*)(OV + rowbase + (size_t)c * SEQ + s0) = v;
            }
        }
    }
}

// ---- kernel 4: flash attention, KVBLK=64 (round-8 change: halve barrier count).
// Round-7 postmortem: 2650 cyc/iter vs ~1150 cyc issue work -> ~55% latency/barrier
// exposure, 2 block-wide barriers per 32-t tile. KVBLK=64 doubles per-iter work
// (16 QK + 20 PV/l MFMA, 32 exp2) at constant per-iter overhead: 32 iters x 2 barriers.
// LDS: 2 bufs x (K 8KB [0,4096) + V 8KB [4096,8192) ushorts) = 32KB -> still
// 2 blocks/CU at 512 blocks. Staging 2 x load_lds16/wave/iter, vmcnt(2) counted
// (never 0 mid-loop; prologue Q-loads are oldest and retire at first wait).
// Swizzles (both-sides): K rows 64 ushorts: slot s holds logical d-chunk s^(t&7);
// V rows now 64 ushorts of t: slot s holds logical t-chunk s^(d&7).
// tau-perm is per-32-block and self-similar: group g=1 (t in [32,64)) uses the
// identical jp mapping feeding V chunks 4..7.
__global__ __launch_bounds__(512, 4) void attn(
    const unsigned short* __restrict__ Q, const unsigned short* __restrict__ K,
    const unsigned short* __restrict__ VTp, unsigned short* __restrict__ O) {
    __shared__ unsigned short kv[2][8192];   // per buf: K [0,4096) + V [4096,8192)
    unsigned short* kvf = &kv[0][0];
    int tid = threadIdx.x;
    int lane = tid & 63, wave = tid >> 6;   // 8 waves
    int quad = lane >> 4, l16 = lane & 15;
    // 512 blocks: id = bh_low*64 + qblk*8 + xcd (8 blocks of a bh share an XCD/L2)
    int id = blockIdx.x;
    int bh = (id & 7) * 8 + (id >> 6);
    int qblk = (id >> 3) & 7;
    int b = bh >> 4, h = bh & 15;
    int q0 = qblk * 256 + wave * 32;
    const unsigned short* Qb = Q + (size_t)bh * SEQ * HD;
    const unsigned short* Kb = K + (size_t)bh * SEQ * HD;
    const unsigned short* Vb = VTp + (size_t)bh * HD * SEQ;
    // staging: 16 chunks of 1KB per buf (K 8 + V 8); wave<4 -> K chunks wave*2+{0,1},
    // wave>=4 -> V chunks (wave-4)*2+{0,1}. Chunk c = 8 rows x 128B; lane ->
    // (row c*8 + lane>>3, slot lane&7); source pre-swizzled: logical chunk =
    // slot ^ (row&7), row&7 == lane>>3.
    int wk = wave & 3, lrow = lane >> 3, lslot = lane & 7;
    const unsigned short *src0, *src1;
    int dst0, dst1, src_step;
    {
        int c0 = wk*2, c1 = wk*2 + 1;
        int r0 = c0*8 + lrow, r1 = c1*8 + lrow;
        int sc = (lslot ^ lrow) * 8;
        if (wave < 4) {
            src0 = Kb + (size_t)r0 * HD + sc;
            src1 = Kb + (size_t)r1 * HD + sc;
            dst0 = c0*512; dst1 = c1*512;
            src_step = 64 * HD;                  // t advances by 64
        } else {
            src0 = Vb + (size_t)r0 * SEQ + sc;
            src1 = Vb + (size_t)r1 * SEQ + sc;
            dst0 = 4096 + c0*512; dst1 = 4096 + c1*512;
            src_step = 64;                       // t advances by 64
        }
    }
    short8 qf[2][2];
    #pragma unroll
    for (int mt=0;mt<2;mt++) {
        const unsigned short* qp = Qb + (size_t)(q0 + mt*16 + l16) * HD + quad*8;
        qf[mt][0] = *(const short8*)(qp);
        qf[mt][1] = *(const short8*)(qp + 32);
    }
    floatx4 o_acc[2][4], l_acc[2];
    #pragma unroll
    for (int mt=0;mt<2;mt++) {
        l_acc[mt] = (floatx4){0.f,0.f,0.f,0.f};
        #pragma unroll
        for (int dt=0;dt<4;dt++) o_acc[mt][dt] = (floatx4){0.f,0.f,0.f,0.f};
    }
    short8 ones;
    #pragma unroll
    for (int jj=0;jj<8;jj++) ones[jj] = (short)0x3F80;   // bf16 1.0
    // swizzled LDS read offsets (ushort units, relative to buf base)
    int koff[4][2], voff[4][2];
    #pragma unroll
    for (int nt=0;nt<4;nt++) {
        int t = nt*16 + l16;
        #pragma unroll
        for (int hh=0;hh<2;hh++)
            koff[nt][hh] = t*64 + ((hh*4 + quad) ^ (t & 7)) * 8;
    }
    #pragma unroll
    for (int dt=0;dt<4;dt++) {
        int d = dt*16 + l16;
        #pragma unroll
        for (int g=0;g<2;g++)
            voff[dt][g] = 4096 + d*64 + ((g*4 + quad) ^ (d & 7)) * 8;
    }

    // prologue: stage tile 0 into buf 0
    load_lds16(src0, kvf + dst0);
    load_lds16(src1, kvf + dst1);
    src0 += src_step; src1 += src_step;

    for (int it = 0; it < 32; ++it) {
        const unsigned short* kb = kvf + (it & 1) * 8192;
        if (it < 31) {
            int bo = ((it & 1) ^ 1) * 8192;
            load_lds16(src0, kvf + bo + dst0);
            load_lds16(src1, kvf + bo + dst1);
            src0 += src_step; src1 += src_step;
            asm volatile("s_waitcnt vmcnt(2)" ::: "memory");
        } else {
            asm volatile("s_waitcnt vmcnt(0)" ::: "memory");
        }
        __builtin_amdgcn_s_barrier();
        asm volatile("" ::: "memory");
        // S^T[t][q]: A = K rows (m = t), B = Q rows (n = q); kf transient per nt
        floatx4 sacc[4][2];
        __builtin_amdgcn_s_setprio(1);
        #pragma unroll
        for (int nt=0;nt<4;nt++) {
            short8 kf0 = *(const short8*)(kb + koff[nt][0]);
            short8 kf1 = *(const short8*)(kb + koff[nt][1]);
            #pragma unroll
            for (int mt=0;mt<2;mt++) {
                floatx4 s = (floatx4){0.f,0.f,0.f,0.f};
                s = __builtin_amdgcn_mfma_f32_16x16x32_bf16(kf0, qf[mt][0], s, 0, 0, 0);
                s = __builtin_amdgcn_mfma_f32_16x16x32_bf16(kf1, qf[mt][1], s, 0, 0, 0);
                sacc[nt][mt] = s;
            }
        }
        __builtin_amdgcn_s_setprio(0);
        // P^T fragments: group g covers t in [g*32,(g+1)*32); slot j = (nt-2g)*4+r
        // (matched by per-32-block tau-perm); pack via v_cvt_pk_bf16_f32
        short8 pf[2][2];
        #pragma unroll
        for (int mt=0;mt<2;mt++)
          #pragma unroll
          for (int g=0;g<2;g++) {
            uintx4 pu;
            #pragma unroll
            for (int jp=0;jp<4;jp++) {
                int nt = g*2 + (jp >> 1), rp = (jp & 1) * 2;
                float e0 = __builtin_amdgcn_exp2f(sacc[nt][mt][rp]);
                float e1 = __builtin_amdgcn_exp2f(sacc[nt][mt][rp+1]);
                unsigned int w;
                asm("v_cvt_pk_bf16_f32 %0, %1, %2" : "=v"(w) : "v"(e0), "v"(e1));
                pu[jp] = w;
            }
            pf[mt][g] = __builtin_bit_cast(short8, pu);
          }
        __builtin_amdgcn_s_setprio(1);
        #pragma unroll
        for (int mt=0;mt<2;mt++) {
            l_acc[mt] = __builtin_amdgcn_mfma_f32_16x16x32_bf16(ones, pf[mt][0], l_acc[mt], 0, 0, 0);
            l_acc[mt] = __builtin_amdgcn_mfma_f32_16x16x32_bf16(ones, pf[mt][1], l_acc[mt], 0, 0, 0);
        }
        #pragma unroll
        for (int dt=0;dt<4;dt++)
          #pragma unroll
          for (int g=0;g<2;g++) {
            short8 vf = *(const short8*)(kb + voff[dt][g]);
            #pragma unroll
            for (int mt=0;mt<2;mt++)
                o_acc[mt][dt] = __builtin_amdgcn_mfma_f32_16x16x32_bf16(vf, pf[mt][g], o_acc[mt][dt], 0, 0, 0);
          }
        __builtin_amdgcn_s_setprio(0);
        asm volatile("" ::: "memory");
        __builtin_amdgcn_s_barrier();   // all reads of this buf done before next overwrite
    }
    // epilogue: o_acc[mt][dt][r] = O^T[d = dt*16+quad*4+r][q = mt*16+l16]; l replicated
    #pragma unroll
    for (int mt=0;mt<2;mt++) {
        float inv = 1.f / l_acc[mt][0];
        int s = q0 + mt*16 + l16;
        #pragma unroll
        for (int dt=0;dt<4;dt++) {
            ushort4 w;
            w.x = f2bf(o_acc[mt][dt][0]*inv);
            w.y = f2bf(o_acc[mt][dt][1]*inv);
            w.z = f2bf(o_acc[mt][dt][2]*inv);
            w.w = f2bf(o_acc[mt][dt][3]*inv);
            *(ushort4*)(O + ((size_t)b*SEQ + s)*EMBED + h*HD + dt*16 + quad*4) = w;
        }
    }
}

extern "C" void kernel_launch(void* const* d_in, const int* in_sizes, int n_in,
                              void* d_out, int out_size, void* d_ws, size_t ws_size,
                              hipStream_t stream) {
    const float* x  = (const float*)d_in[0];
    const float* Wq = (const float*)d_in[1]; const float* bq = (const float*)d_in[2];
    const float* Wk = (const float*)d_in[3]; const float* bk = (const float*)d_in[4];
    const float* Wv = (const float*)d_in[5]; const float* bv = (const float*)d_in[6];
    const float* Wo = (const float*)d_in[7]; const float* bo = (const float*)d_in[8];
    char* ws = (char*)d_ws;
    unsigned short* xb  = (unsigned short*)(ws);                      // 16 MB, reused as O later
    unsigned short* WqT = (unsigned short*)(ws + (16ull<<20));        // 2 MB each; Wq|Wk|Wv contiguous
    unsigned short* WkT = (unsigned short*)(ws + (18ull<<20));
    unsigned short* WvT = (unsigned short*)(ws + (20ull<<20));
    unsigned short* WoT = (unsigned short*)(ws + (22ull<<20));
    unsigned short* Qb  = (unsigned short*)(ws + (24ull<<20));        // 16 MB
    unsigned short* Kb  = (unsigned short*)(ws + (40ull<<20));        // 16 MB
    unsigned short* VTb = (unsigned short*)(ws + (56ull<<20));        // 16 MB  (total 72 MB)
    unsigned short* Ob  = xb;   // xb dead after QKV GEMM; reuse for attention output

    cvt_x<<<(M_TOT*EMBED)/1024, 256, 0, stream>>>(x, xb);
    wtrans<<<dim3(32,32,4), dim3(32,8), 0, stream>>>(Wq,Wk,Wv,Wo, WqT,WkT,WvT,WoT);
    // fused QKV: BT = WqT|WkT|WvT (contiguous), N = 3072 -> 64x24 = 1536 blocks,
    // 2 blocks/CU -> exactly 3 full passes
    gemmk<0><<<dim3(1536), 512, 0, stream>>>(xb, WqT, bq, bk, bv, Qb, Kb, VTb);
    attn<<<dim3(512), 512, 0, stream>>>(Qb, Kb, VTb, Ob);
    // out-proj: 64x8 = 512 blocks, 2 blocks/CU -> exactly 1 full pass
    gemmk<1><<<dim3(512), 512, 0, stream>>>(Ob, WoT, bo, bo, bo, (float*)d_out, nullptr, nullptr);
}

// Round 10
// 250.813 us; speedup vs baseline: 1.0373x; 1.0373x over previous
//
#include <hip/hip_runtime.h>
#include <stdint.h>

#define EMBED 1024
#define NH 16
#define HD 64
#define SEQ 2048
#define BATCH 4
#define M_TOT (BATCH*SEQ)   // 8192
#define QSCALE 0.18033688011112042f   // log2(e)/sqrt(HD)

typedef __attribute__((ext_vector_type(8))) short short8;
typedef __attribute__((ext_vector_type(4))) float floatx4;
typedef __attribute__((ext_vector_type(4))) unsigned int uintx4;

__device__ __forceinline__ unsigned short f2bf(float f) {
    union { float f; unsigned int u; } v; v.f = f;
    unsigned int r = v.u + 0x7fffu + ((v.u >> 16) & 1u);
    return (unsigned short)(r >> 16);
}

__device__ __forceinline__ void load_lds16(const unsigned short* g, unsigned short* l) {
    __builtin_amdgcn_global_load_lds(
        (const __attribute__((address_space(1))) unsigned int*)g,
        (__attribute__((address_space(3))) unsigned int*)l, 16, 0, 0);
}

// ---- kernel 1: x fp32 -> bf16 ----
__global__ void cvt_x(const float* __restrict__ x, unsigned short* __restrict__ xb) {
    int i = (blockIdx.x * 256 + threadIdx.x) * 4;
    float4 v = *(const float4*)(x + i);
    ushort4 o;
    o.x = f2bf(v.x); o.y = f2bf(v.y); o.z = f2bf(v.z); o.w = f2bf(v.w);
    *(ushort4*)(xb + i) = o;
}

// ---- kernel 2: transpose W [k][n] fp32 -> WT [n][k] bf16 ----
__global__ void wtrans(const float* __restrict__ w0, const float* __restrict__ w1,
                       const float* __restrict__ w2, const float* __restrict__ w3,
                       unsigned short* __restrict__ t0, unsigned short* __restrict__ t1,
                       unsigned short* __restrict__ t2, unsigned short* __restrict__ t3) {
    __shared__ float tile[32][33];
    const float* W; unsigned short* T;
    switch (blockIdx.z) { case 0: W=w0; T=t0; break; case 1: W=w1; T=t1; break;
                          case 2: W=w2; T=t2; break; default: W=w3; T=t3; }
    int n0 = blockIdx.x * 32, k0 = blockIdx.y * 32;
    int tx = threadIdx.x, ty = threadIdx.y;
    #pragma unroll
    for (int i = 0; i < 4; i++)
        tile[ty + i*8][tx] = W[(k0 + ty + i*8) * EMBED + n0 + tx];
    __syncthreads();
    #pragma unroll
    for (int i = 0; i < 4; i++)
        T[(n0 + ty + i*8) * EMBED + k0 + tx] = f2bf(tile[tx][ty + i*8]);
}

// ---- kernel 3a: 256x128 QKV GEMM, BK=32, 3-buffer distance-2 pipeline.
// Raise MFMA per LDS byte: wave tile 128x32 (2m x 4n waves): 16 MFMA per
// 10 ds_read_b128 (vs 8 per 6 at 128^2) -> 40B/KFLOP, 2x MFMA per barrier.
// acc[8][2]=64 AGPR + ~55 arch VGPR ~ 119 unified < 128 cap (launch_bounds(512,4)).
// LDS 3 bufs x 24KB = 72KB -> 2 blocks/CU (144KB <= 160KB).
// Schedule per tile t: {10 ds_read; stage t+2 -> buf (t+2)%3 (3 gloads: A x2, B x1);
// 16 MFMA; vmcnt(3); s_barrier}. vmcnt(3) completes st(t+1), leaves st(t+2) in
// flight. WAR: buf((t+2)%3)=buf((t-1)%3), read at t-1, retired before
// barrier(t-1) which precedes this stage. Tail: t=30 vmcnt(0), t=31 none.
// Swizzle (both sides): row r = 64B = 4 slots of 16B; slot s holds logical chunk
// s ^ f(r), f(r)=(r&3)^((r>>2)&3) (conflict-free, round-7 verified: conflicts=0).
// Grid 768 = 8 XCD x 4 mb x 24 nb; A-stripe 2MB L2-resident; B-block reused 4x.
// which = nblk>>10: 0 -> Qb bf16 [B,H,S,D]*QSCALE; 1 -> Kb; 2 -> VTp [B,H,D,SEQ]
// tau-perm via padded LDS transpose (stride 264 ushorts, max idx 33783 < 36864).
#define G2BUFS 12288   // ushorts per buffer: A 256x32 (8192) | B 128x32 (4096)

template<bool STG, int WAITN>
__device__ __forceinline__ void ktile2(int t,
        const unsigned short* Abase, const unsigned short* Bbase,
        const unsigned short* Asrc, const unsigned short* Bsrc,
        unsigned short* sda, unsigned short* sdb, floatx4 (&acc)[8][2]) {
    const int bo = (t % 3) * G2BUFS;
    short8 fA[8], fB[2];
    #pragma unroll
    for (int m=0;m<8;m++) fA[m] = *(const short8*)(Abase + bo + m*512);
    #pragma unroll
    for (int n=0;n<2;n++) fB[n] = *(const short8*)(Bbase + bo + n*512);
    if (STG) {
        const int buf_ = (t+2) % 3; const int ko_ = (t+2)*32;
        load_lds16(Asrc + ko_,             sda + buf_*G2BUFS);
        load_lds16(Asrc + 128*EMBED + ko_, sda + buf_*G2BUFS + 4096);
        load_lds16(Bsrc + ko_,             sdb + buf_*G2BUFS);
    }
    #pragma unroll
    for (int m=0;m<8;m++)
      #pragma unroll
      for (int n=0;n<2;n++)
        acc[m][n] = __builtin_amdgcn_mfma_f32_16x16x32_bf16(fA[m], fB[n], acc[m][n], 0,0,0);
    if (WAITN == 3)      { asm volatile("s_waitcnt vmcnt(3)" ::: "memory"); asm volatile("s_barrier" ::: "memory"); }
    else if (WAITN == 0) { asm volatile("s_waitcnt vmcnt(0)" ::: "memory"); asm volatile("s_barrier" ::: "memory"); }
}

__global__ __launch_bounds__(512, 4) void gemm256(
        const unsigned short* __restrict__ A, const unsigned short* __restrict__ BT,
        const float* __restrict__ b0, const float* __restrict__ b1, const float* __restrict__ b2,
        void* __restrict__ o0, void* __restrict__ o1, void* __restrict__ o2) {
    __shared__ unsigned short lds[3*G2BUFS];   // 72KB
    const int tid = threadIdx.x;
    const int lane = tid & 63, wave = tid >> 6;
    const int quad = lane >> 4, l16 = lane & 15;
    const int wm = wave >> 2, wn = wave & 3;   // wave tile 128x32 at (wm*128, wn*32)
    const int id = blockIdx.x;
    const int xcd = id & 7, j = id >> 3;
    const int mblk = (xcd * 4 + (j & 3)) * 256;
    const int nblk = (j >> 2) * 128;

    // staging: thread tid = (row tid>>2, slot tid&3); slot s holds logical chunk
    // s ^ f(row) (inverse-swizzled source). A: 2 issues (rows 0-127, 128-255); B: 1.
    const int srow = tid >> 2;
    const int scol = ((tid & 3) ^ (srow & 3) ^ ((srow >> 2) & 3)) * 8;
    const unsigned short* Asrc = A  + (size_t)(mblk + srow) * EMBED + scol;
    const unsigned short* Bsrc = BT + (size_t)(nblk + srow) * EMBED + scol;
    unsigned short* sda = lds + wave * 512;            // wave stages 16 rows/issue
    unsigned short* sdb = lds + 8192 + wave * 512;

    // swizzled fragment read: row ..+l16, logical chunk quad at slot quad ^ f(l16)
    const int cs = (quad ^ (l16 & 3) ^ ((l16 >> 2) & 3)) * 8;
    const unsigned short* Abase = lds + (wm*128 + l16)*32 + cs;
    const unsigned short* Bbase = lds + 8192 + (wn*32 + l16)*32 + cs;

    floatx4 acc[8][2];
    #pragma unroll
    for (int m=0;m<8;m++)
      #pragma unroll
      for (int n=0;n<2;n++) acc[m][n] = (floatx4){0.f,0.f,0.f,0.f};

    // prologue: stage tiles 0,1 (6 loads); vmcnt(3) completes tile 0 only
    #pragma unroll
    for (int p=0;p<2;p++) {
        load_lds16(Asrc + p*32,             sda + p*G2BUFS);
        load_lds16(Asrc + 128*EMBED + p*32, sda + p*G2BUFS + 4096);
        load_lds16(Bsrc + p*32,             sdb + p*G2BUFS);
    }
    asm volatile("s_waitcnt vmcnt(3)" ::: "memory");
    asm volatile("s_barrier" ::: "memory");

    #pragma unroll 3
    for (int t = 0; t < 30; ++t)
        ktile2<true,3>(t, Abase, Bbase, Asrc, Bsrc, sda, sdb, acc);
    ktile2<false,0>(30, Abase, Bbase, Asrc, Bsrc, sda, sdb, acc);
    ktile2<false,-1>(31, Abase, Bbase, Asrc, Bsrc, sda, sdb, acc);

    // epilogue: C/D layout col=lane&15, row=quad*4+reg; which uniform per block
    int which = nblk >> 10;
    const float* bs = (which==0) ? b0 : (which==1) ? b1 : b2;
    if (which < 2) {
        unsigned short* O = (unsigned short*)((which==0) ? o0 : o1);
        float sc = (which==0) ? QSCALE : 1.f;
        #pragma unroll
        for (int mt=0;mt<8;mt++)
          #pragma unroll
          for (int nt=0;nt<2;nt++) {
            int coll = (nblk & 1023) + wn*32 + nt*16 + l16;
            float bv = bs[coll];
            int h = coll >> 6, d = coll & 63;
            #pragma unroll
            for (int r=0;r<4;r++) {
                int row = mblk + wm*128 + mt*16 + quad*4 + r;
                int b = row >> 11, s = row & 2047;
                O[((size_t)(b*NH + h)*SEQ + s)*HD + d] = f2bf((acc[mt][nt][r] + bv) * sc);
            }
          }
    } else {
        // V: padded LDS transpose (T[c][sp], stride 264 ushorts = 528B, 16B-aligned,
        // bank-rotating). tau-perm on the write side within each 32-row block:
        // p = ((s>>2)&3)*8 + ((s>>4)&1)*4 + (s&3). Readback: coalesced 16B stores.
        unsigned short* T = lds;
        unsigned short* OV = (unsigned short*)o2;
        size_t rowbase = ((size_t)((mblk >> 11)*1024 + (nblk & 1023))) * SEQ + (mblk & 2047);
        __syncthreads();     // all K-loop LDS reads complete before overwrite
        #pragma unroll
        for (int nt=0;nt<2;nt++) {
            int cloc = wn*32 + nt*16 + l16;            // local col 0..127
            float bv = bs[(nblk & 1023) + cloc];
            #pragma unroll
            for (int mt=0;mt<8;mt++) {
                int row0 = wm*128 + mt*16 + quad*4;    // local row 0..252, mult of 4
                int sp0 = (row0 & ~31) | (((row0 >> 2) & 3) << 3) | (((row0 >> 4) & 1) << 2);
                ushort4 w;
                w.x = f2bf(acc[mt][nt][0] + bv);
                w.y = f2bf(acc[mt][nt][1] + bv);
                w.z = f2bf(acc[mt][nt][2] + bv);
                w.w = f2bf(acc[mt][nt][3] + bv);
                *(ushort4*)(T + cloc*264 + sp0) = w;
            }
        }
        __syncthreads();
        int s0 = (lane & 31) * 8, dloc = lane >> 5;    // 32 s-chunks x 2 cols
        #pragma unroll
        for (int i=0;i<8;i++) {
            int c = wave*16 + i*2 + dloc;              // local col 0..127
            short8 v = *(const short8*)(T + c*264 + s0);
            *(short8*)(OV + rowbase + (size_t)c * SEQ + s0) = v;
        }
    }
}

// ---- kernel 3b: 128x128 GEMM for out-proj (round-7 structure: 4-buffer
// distance-3 pipeline, conflict-free swizzle, 512 blocks = 1 full pass).
#define GBUFS 8192   // ushorts per K-tile buffer (16KB: A 128x32 | B 128x32)

template<bool STG, int WAITN>
__device__ __forceinline__ void ktile(int t,
        const unsigned short* Abase, const unsigned short* Bbase,
        const unsigned short* Asrc, const unsigned short* Bsrc,
        unsigned short* sda, unsigned short* sdb, floatx4 (&acc)[4][2]) {
    const int bo = (t & 3) * GBUFS;
    short8 fA[4], fB[2];
    #pragma unroll
    for (int m=0;m<4;m++) fA[m] = *(const short8*)(Abase + bo + m*512);
    #pragma unroll
    for (int n=0;n<2;n++) fB[n] = *(const short8*)(Bbase + bo + n*512);
    if (STG) {
        const int buf_ = (t+3) & 3; const int ko_ = (t+3)*32;
        load_lds16(Asrc + ko_, sda + buf_*GBUFS);
        load_lds16(Bsrc + ko_, sdb + buf_*GBUFS);
    }
    #pragma unroll
    for (int m=0;m<4;m++)
      #pragma unroll
      for (int n=0;n<2;n++)
        acc[m][n] = __builtin_amdgcn_mfma_f32_16x16x32_bf16(fA[m], fB[n], acc[m][n], 0,0,0);
    if (WAITN == 4)      { asm volatile("s_waitcnt vmcnt(4)" ::: "memory"); asm volatile("s_barrier" ::: "memory"); }
    else if (WAITN == 2) { asm volatile("s_waitcnt vmcnt(2)" ::: "memory"); asm volatile("s_barrier" ::: "memory"); }
    else if (WAITN == 0) { asm volatile("s_waitcnt vmcnt(0)" ::: "memory"); asm volatile("s_barrier" ::: "memory"); }
}

__global__ __launch_bounds__(512, 4) void gemmk(
        const unsigned short* __restrict__ A, const unsigned short* __restrict__ BT,
        const float* __restrict__ b0, float* __restrict__ O) {
    constexpr int BM = 128, BN = 128;
    __shared__ unsigned short lds[4*GBUFS];    // 64KB: 4 bufs
    const int tid = threadIdx.x;
    const int lane = tid & 63, wave = tid >> 6;
    const int quad = lane >> 4, l16 = lane & 15;
    const int wm = wave >> 2, wn = wave & 3;   // wave tile 64x32 at (wm*64, wn*32)
    const int id = blockIdx.x;
    constexpr int MS = (M_TOT/BM)/8;           // 8 m-blocks per XCD stripe
    const int xcd = id & 7, j = id >> 3;
    const int mblk = (xcd * MS + (j % MS)) * BM;
    const int nblk = (j / MS) * BN;

    const int srow = tid >> 2;
    const int scol = ((tid & 3) ^ (srow & 3) ^ ((srow >> 2) & 3)) * 8;
    const unsigned short* Asrc = A  + (size_t)(mblk + srow) * EMBED + scol;
    const unsigned short* Bsrc = BT + (size_t)(nblk + srow) * EMBED + scol;
    unsigned short* sda = lds + wave * 512;
    unsigned short* sdb = lds + BM*32 + wave * 512;

    const int cs = (quad ^ (l16 & 3) ^ ((l16 >> 2) & 3)) * 8;
    const unsigned short* Abase = lds + (wm*64 + l16)*32 + cs;
    const unsigned short* Bbase = lds + BM*32 + (wn*32 + l16)*32 + cs;

    floatx4 acc[4][2];
    #pragma unroll
    for (int m=0;m<4;m++)
      #pragma unroll
      for (int n=0;n<2;n++) acc[m][n] = (floatx4){0.f,0.f,0.f,0.f};

    #pragma unroll
    for (int p=0;p<3;p++) {
        load_lds16(Asrc + p*32, sda + p*GBUFS);
        load_lds16(Bsrc + p*32, sdb + p*GBUFS);
    }
    asm volatile("s_waitcnt vmcnt(4)" ::: "memory");
    asm volatile("s_barrier" ::: "memory");

    #pragma unroll 4
    for (int t = 0; t < 28; ++t)
        ktile<true,4>(t, Abase, Bbase, Asrc, Bsrc, sda, sdb, acc);
    ktile<true, 4>(28, Abase, Bbase, Asrc, Bsrc, sda, sdb, acc);  // stages ST(31)
    ktile<false,2>(29, Abase, Bbase, Asrc, Bsrc, sda, sdb, acc);
    ktile<false,0>(30, Abase, Bbase, Asrc, Bsrc, sda, sdb, acc);
    ktile<false,-1>(31, Abase, Bbase, Asrc, Bsrc, sda, sdb, acc);

    // epilogue: fp32 out + bias
    #pragma unroll
    for (int mt=0;mt<4;mt++)
      #pragma unroll
      for (int nt=0;nt<2;nt++) {
        int col = nblk + wn*32 + nt*16 + l16;
        float bv = b0[col];
        #pragma unroll
        for (int r=0;r<4;r++) {
            int row = mblk + wm*64 + mt*16 + quad*4 + r;
            O[(size_t)row * EMBED + col] = acc[mt][nt][r] + bv;
        }
      }
}

// ---- kernel 4: flash attention, KVBLK=64 (round 8: 68.9us, conflicts 0,
// ~1000 TF effective -- at the plain-HIP ladder frontier).
__global__ __launch_bounds__(512, 4) void attn(
    const unsigned short* __restrict__ Q, const unsigned short* __restrict__ K,
    const unsigned short* __restrict__ VTp, unsigned short* __restrict__ O) {
    __shared__ unsigned short kv[2][8192];   // per buf: K [0,4096) + V [4096,8192)
    unsigned short* kvf = &kv[0][0];
    int tid = threadIdx.x;
    int lane = tid & 63, wave = tid >> 6;   // 8 waves
    int quad = lane >> 4, l16 = lane & 15;
    // 512 blocks: id = bh_low*64 + qblk*8 + xcd (8 blocks of a bh share an XCD/L2)
    int id = blockIdx.x;
    int bh = (id & 7) * 8 + (id >> 6);
    int qblk = (id >> 3) & 7;
    int b = bh >> 4, h = bh & 15;
    int q0 = qblk * 256 + wave * 32;
    const unsigned short* Qb = Q + (size_t)bh * SEQ * HD;
    const unsigned short* Kb = K + (size_t)bh * SEQ * HD;
    const unsigned short* Vb = VTp + (size_t)bh * HD * SEQ;
    // staging: 16 chunks of 1KB per buf (K 8 + V 8); wave<4 -> K chunks wave*2+{0,1},
    // wave>=4 -> V chunks (wave-4)*2+{0,1}. Chunk c = 8 rows x 128B; lane ->
    // (row c*8 + lane>>3, slot lane&7); source pre-swizzled: logical chunk =
    // slot ^ (row&7), row&7 == lane>>3.
    int wk = wave & 3, lrow = lane >> 3, lslot = lane & 7;
    const unsigned short *src0, *src1;
    int dst0, dst1, src_step;
    {
        int c0 = wk*2, c1 = wk*2 + 1;
        int r0 = c0*8 + lrow, r1 = c1*8 + lrow;
        int sc = (lslot ^ lrow) * 8;
        if (wave < 4) {
            src0 = Kb + (size_t)r0 * HD + sc;
            src1 = Kb + (size_t)r1 * HD + sc;
            dst0 = c0*512; dst1 = c1*512;
            src_step = 64 * HD;                  // t advances by 64
        } else {
            src0 = Vb + (size_t)r0 * SEQ + sc;
            src1 = Vb + (size_t)r1 * SEQ + sc;
            dst0 = 4096 + c0*512; dst1 = 4096 + c1*512;
            src_step = 64;                       // t advances by 64
        }
    }
    short8 qf[2][2];
    #pragma unroll
    for (int mt=0;mt<2;mt++) {
        const unsigned short* qp = Qb + (size_t)(q0 + mt*16 + l16) * HD + quad*8;
        qf[mt][0] = *(const short8*)(qp);
        qf[mt][1] = *(const short8*)(qp + 32);
    }
    floatx4 o_acc[2][4], l_acc[2];
    #pragma unroll
    for (int mt=0;mt<2;mt++) {
        l_acc[mt] = (floatx4){0.f,0.f,0.f,0.f};
        #pragma unroll
        for (int dt=0;dt<4;dt++) o_acc[mt][dt] = (floatx4){0.f,0.f,0.f,0.f};
    }
    short8 ones;
    #pragma unroll
    for (int jj=0;jj<8;jj++) ones[jj] = (short)0x3F80;   // bf16 1.0
    // swizzled LDS read offsets (ushort units, relative to buf base)
    int koff[4][2], voff[4][2];
    #pragma unroll
    for (int nt=0;nt<4;nt++) {
        int t = nt*16 + l16;
        #pragma unroll
        for (int hh=0;hh<2;hh++)
            koff[nt][hh] = t*64 + ((hh*4 + quad) ^ (t & 7)) * 8;
    }
    #pragma unroll
    for (int dt=0;dt<4;dt++) {
        int d = dt*16 + l16;
        #pragma unroll
        for (int g=0;g<2;g++)
            voff[dt][g] = 4096 + d*64 + ((g*4 + quad) ^ (d & 7)) * 8;
    }

    // prologue: stage tile 0 into buf 0
    load_lds16(src0, kvf + dst0);
    load_lds16(src1, kvf + dst1);
    src0 += src_step; src1 += src_step;

    for (int it = 0; it < 32; ++it) {
        const unsigned short* kb = kvf + (it & 1) * 8192;
        if (it < 31) {
            int bo = ((it & 1) ^ 1) * 8192;
            load_lds16(src0, kvf + bo + dst0);
            load_lds16(src1, kvf + bo + dst1);
            src0 += src_step; src1 += src_step;
            asm volatile("s_waitcnt vmcnt(2)" ::: "memory");
        } else {
            asm volatile("s_waitcnt vmcnt(0)" ::: "memory");
        }
        __builtin_amdgcn_s_barrier();
        asm volatile("" ::: "memory");
        // S^T[t][q]: A = K rows (m = t), B = Q rows (n = q); kf transient per nt
        floatx4 sacc[4][2];
        __builtin_amdgcn_s_setprio(1);
        #pragma unroll
        for (int nt=0;nt<4;nt++) {
            short8 kf0 = *(const short8*)(kb + koff[nt][0]);
            short8 kf1 = *(const short8*)(kb + koff[nt][1]);
            #pragma unroll
            for (int mt=0;mt<2;mt++) {
                floatx4 s = (floatx4){0.f,0.f,0.f,0.f};
                s = __builtin_amdgcn_mfma_f32_16x16x32_bf16(kf0, qf[mt][0], s, 0, 0, 0);
                s = __builtin_amdgcn_mfma_f32_16x16x32_bf16(kf1, qf[mt][1], s, 0, 0, 0);
                sacc[nt][mt] = s;
            }
        }
        __builtin_amdgcn_s_setprio(0);
        // P^T fragments: group g covers t in [g*32,(g+1)*32); slot j = (nt-2g)*4+r
        // (matched by per-32-block tau-perm); pack via v_cvt_pk_bf16_f32
        short8 pf[2][2];
        #pragma unroll
        for (int mt=0;mt<2;mt++)
          #pragma unroll
          for (int g=0;g<2;g++) {
            uintx4 pu;
            #pragma unroll
            for (int jp=0;jp<4;jp++) {
                int nt = g*2 + (jp >> 1), rp = (jp & 1) * 2;
                float e0 = __builtin_amdgcn_exp2f(sacc[nt][mt][rp]);
                float e1 = __builtin_amdgcn_exp2f(sacc[nt][mt][rp+1]);
                unsigned int w;
                asm("v_cvt_pk_bf16_f32 %0, %1, %2" : "=v"(w) : "v"(e0), "v"(e1));
                pu[jp] = w;
            }
            pf[mt][g] = __builtin_bit_cast(short8, pu);
          }
        __builtin_amdgcn_s_setprio(1);
        #pragma unroll
        for (int mt=0;mt<2;mt++) {
            l_acc[mt] = __builtin_amdgcn_mfma_f32_16x16x32_bf16(ones, pf[mt][0], l_acc[mt], 0, 0, 0);
            l_acc[mt] = __builtin_amdgcn_mfma_f32_16x16x32_bf16(ones, pf[mt][1], l_acc[mt], 0, 0, 0);
        }
        #pragma unroll
        for (int dt=0;dt<4;dt++)
          #pragma unroll
          for (int g=0;g<2;g++) {
            short8 vf = *(const short8*)(kb + voff[dt][g]);
            #pragma unroll
            for (int mt=0;mt<2;mt++)
                o_acc[mt][dt] = __builtin_amdgcn_mfma_f32_16x16x32_bf16(vf, pf[mt][g], o_acc[mt][dt], 0, 0, 0);
          }
        __builtin_amdgcn_s_setprio(0);
        asm volatile("" ::: "memory");
        __builtin_amdgcn_s_barrier();   // all reads of this buf done before next overwrite
    }
    // epilogue: o_acc[mt][dt][r] = O^T[d = dt*16+quad*4+r][q = mt*16+l16]; l replicated
    #pragma unroll
    for (int mt=0;mt<2;mt++) {
        float inv = 1.f / l_acc[mt][0];
        int s = q0 + mt*16 + l16;
        #pragma unroll
        for (int dt=0;dt<4;dt++) {
            ushort4 w;
            w.x = f2bf(o_acc[mt][dt][0]*inv);
            w.y = f2bf(o_acc[mt][dt][1]*inv);
            w.z = f2bf(o_acc[mt][dt][2]*inv);
            w.w = f2bf(o_acc[mt][dt][3]*inv);
            *(ushort4*)(O + ((size_t)b*SEQ + s)*EMBED + h*HD + dt*16 + quad*4) = w;
        }
    }
}

extern "C" void kernel_launch(void* const* d_in, const int* in_sizes, int n_in,
                              void* d_out, int out_size, void* d_ws, size_t ws_size,
                              hipStream_t stream) {
    const float* x  = (const float*)d_in[0];
    const float* Wq = (const float*)d_in[1]; const float* bq = (const float*)d_in[2];
    const float* Wk = (const float*)d_in[3]; const float* bk = (const float*)d_in[4];
    const float* Wv = (const float*)d_in[5]; const float* bv = (const float*)d_in[6];
    const float* Wo = (const float*)d_in[7]; const float* bo = (const float*)d_in[8];
    char* ws = (char*)d_ws;
    unsigned short* xb  = (unsigned short*)(ws);                      // 16 MB, reused as O later
    unsigned short* WqT = (unsigned short*)(ws + (16ull<<20));        // 2 MB each; Wq|Wk|Wv contiguous
    unsigned short* WkT = (unsigned short*)(ws + (18ull<<20));
    unsigned short* WvT = (unsigned short*)(ws + (20ull<<20));
    unsigned short* WoT = (unsigned short*)(ws + (22ull<<20));
    unsigned short* Qb  = (unsigned short*)(ws + (24ull<<20));        // 16 MB
    unsigned short* Kb  = (unsigned short*)(ws + (40ull<<20));        // 16 MB
    unsigned short* VTb = (unsigned short*)(ws + (56ull<<20));        // 16 MB  (total 72 MB)
    unsigned short* Ob  = xb;   // xb dead after QKV GEMM; reuse for attention output

    cvt_x<<<(M_TOT*EMBED)/1024, 256, 0, stream>>>(x, xb);
    wtrans<<<dim3(32,32,4), dim3(32,8), 0, stream>>>(Wq,Wk,Wv,Wo, WqT,WkT,WvT,WoT);
    // fused QKV: BT = WqT|WkT|WvT (contiguous), N = 3072 -> 8 XCD x 4 mb x 24 nb = 768 blocks
    gemm256<<<dim3(768), 512, 0, stream>>>(xb, WqT, bq, bk, bv, Qb, Kb, VTb);
    attn<<<dim3(512), 512, 0, stream>>>(Qb, Kb, VTb, Ob);
    // out-proj: 64x8 = 512 blocks, 2 blocks/CU -> exactly 1 full pass
    gemmk<<<dim3(512), 512, 0, stream>>>(Ob, WoT, bo, (float*)d_out);
}